// Round 15
// baseline (128.048 us; speedup 1.0000x reference)
//
#include <hip/hip_runtime.h>
#include <stdint.h>

// Problem geometry (fixed)
#define HW     16384      // 128*128
#define IMGW   128
#define NCH    768        // 3*DIM
#define DIMC   256
#define NB     2
#define CPH    32         // channels per head

typedef unsigned short u16;
typedef unsigned int   u32;
typedef __attribute__((ext_vector_type(8))) short bf16x8;
typedef __attribute__((ext_vector_type(4))) float f32x4;

__device__ __forceinline__ float bf2f(u16 u) { return __uint_as_float(((u32)u) << 16); }
__device__ __forceinline__ u16 f2bf(float f) {
    u32 u = __float_as_uint(f);
    u += 0x7fffu + ((u >> 16) & 1u);
    return (u16)(u >> 16);
}

#define GLOAD16(gp, lp) __builtin_amdgcn_global_load_lds( \
    (const __attribute__((address_space(1))) void*)(gp),  \
    (__attribute__((address_space(3))) void*)(lp), 16, 0, 0)

// ---------------------------------------------------------------------------
// T1+T2 merged (prep_inputs):
// blocks [0,2048): transpose + split x (fp32) -> xT hi/lo bf16,
//   layout [b*8+s][16384 n][32 c], quad-swizzled (slot u holds quad u^((n>>1)&3))
// blocks [2048,2072): split W_qkv -> hi/lo bf16, layout [s=8][768 m][32 c],
//   quad-swizzled (slot u holds quad u^((m>>1)&3))
// ---------------------------------------------------------------------------
__global__ __launch_bounds__(256)
void prep_inputs(const float* __restrict__ x, const float* __restrict__ w,
                 u16* __restrict__ xth, u16* __restrict__ xtl,
                 u16* __restrict__ wh, u16* __restrict__ wl)
{
    __shared__ float Xs[64][68];
    const int bid = blockIdx.x;
    const int t = threadIdx.x;

    if (bid < 2048) {
        const int bz = bid >> 10;
        const int r  = bid & 1023;
        const int nt = r & 255;
        const int ct = r >> 8;
        const int n0 = nt * 64, c0 = ct * 64;
        const float* xb = x + (size_t)bz * DIMC * HW;

        #pragma unroll
        for (int it = 0; it < 4; ++it) {
            int cl = (t >> 4) + it * 16;
            int nl4 = (t & 15) << 2;
            float4 v = *(const float4*)(xb + (size_t)(c0 + cl) * HW + n0 + nl4);
            Xs[cl][nl4]     = v.x; Xs[cl][nl4 + 1] = v.y;
            Xs[cl][nl4 + 2] = v.z; Xs[cl][nl4 + 3] = v.w;
        }
        __syncthreads();

        const int nl = t >> 2, u = t & 3;
        const int p = (nl >> 1) & 3;                  // n0 is mult of 64
        #pragma unroll
        for (int sl = 0; sl < 2; ++sl) {
            const int s = (c0 >> 5) + sl;
            const int cb = sl * 32 + ((u ^ p) << 3);
            u32 hq[4], lq[4];
            #pragma unroll
            for (int e2 = 0; e2 < 4; ++e2) {
                float f0 = Xs[cb + 2 * e2][nl];
                float f1 = Xs[cb + 2 * e2 + 1][nl];
                u16 h0 = f2bf(f0); u16 l0 = f2bf(f0 - bf2f(h0));
                u16 h1 = f2bf(f1); u16 l1 = f2bf(f1 - bf2f(h1));
                hq[e2] = (u32)h0 | ((u32)h1 << 16);
                lq[e2] = (u32)l0 | ((u32)l1 << 16);
            }
            size_t rowb = ((size_t)((bz * 8 + s)) * 16384 + n0 + nl) << 6;
            uint4 hv = {hq[0], hq[1], hq[2], hq[3]};
            uint4 lv = {lq[0], lq[1], lq[2], lq[3]};
            *(uint4*)((char*)xth + rowb + (u << 4)) = hv;
            *(uint4*)((char*)xtl + rowb + (u << 4)) = lv;
        }
    } else {
        const int idx = (bid - 2048) * 256 + t;   // 0..6143
        const int m = idx >> 3, s = idx & 7;
        const int p = (m >> 1) & 3;
        #pragma unroll
        for (int u = 0; u < 4; ++u) {
            const int cb = s * 32 + ((u ^ p) << 3);
            u32 hq[4], lq[4];
            #pragma unroll
            for (int e2 = 0; e2 < 4; ++e2) {
                float f0 = w[m * 256 + cb + 2 * e2];
                float f1 = w[m * 256 + cb + 2 * e2 + 1];
                u16 h0 = f2bf(f0); u16 l0 = f2bf(f0 - bf2f(h0));
                u16 h1 = f2bf(f1); u16 l1 = f2bf(f1 - bf2f(h1));
                hq[e2] = (u32)h0 | ((u32)h1 << 16);
                lq[e2] = (u32)l0 | ((u32)l1 << 16);
            }
            size_t rowb = ((size_t)(s * 768 + m)) << 6;   // 64 B per row
            uint4 hv = {hq[0], hq[1], hq[2], hq[3]};
            uint4 lv = {lq[0], lq[1], lq[2], lq[3]};
            *(uint4*)((char*)wh + rowb + (u << 4)) = hv;
            *(uint4*)((char*)wl + rowb + (u << 4)) = lv;
        }
    }
}

// ---------------------------------------------------------------------------
// K1'/K7': C[bz][m][n] = sum_c A[m][c] * B[bz][c][n] via split-bf16 MFMA.
// LDS 2-phase double-buffered pipeline (stage s+1 before compute s) +
// XCD-chunked block swizzle. Quad-swizzled operand layouts -> conflict-free
// ds_read_b128. FULLB: B hi+lo (3 products). !FULLB: B hi only (2 products).
// ---------------------------------------------------------------------------
template<bool FULLB, bool OUTBF16, int MBLKS>
__global__ __launch_bounds__(256, 2)
void gemm_mfma_split(const u16* __restrict__ Ahp, const u16* __restrict__ Alp,
                     const u16* __restrict__ Bhp, const u16* __restrict__ Blp,
                     void* __restrict__ Cp, int aBatch, int aSlice, long cBatch)
{
    constexpr int BUFSZ = FULLB ? 32768 : 24576;  // {Ah,Al,Bh[,Bl]} x 8KB
    __shared__ char smem[2 * BUFSZ];

    const int t    = threadIdx.x;
    const int lane = t & 63;
    const int w    = t >> 6;
    // XCD-chunked swizzle (nwg % 8 == 0)
    const int per = gridDim.x >> 3;
    const int wid = (blockIdx.x & 7) * per + (blockIdx.x >> 3);
    const int nglob = wid / MBLKS;               // m iterates fastest
    const int m0 = (wid % MBLKS) * 128;
    const int bz = nglob >> 7;
    const int n0 = (nglob & 127) * 128;

    const int lrow  = lane >> 2;       // 0..15
    const int lquad = lane & 3;
    const int mh = w >> 1, nh = w & 1;
    const int swz = ((lane & 15) << 6) + ((((lane >> 4) ^ ((lane >> 1) & 3))) << 4);

    f32x4 acc[4][4];
    #pragma unroll
    for (int i = 0; i < 4; ++i)
        #pragma unroll
        for (int j = 0; j < 4; ++j)
            acc[i][j] = (f32x4){0.f, 0.f, 0.f, 0.f};

    auto stage = [&](int buf, int s) {
        const size_t arow0 = (size_t)bz * aBatch + (size_t)s * aSlice + m0;
        const size_t brow0 = ((size_t)(bz * 8 + s)) * 16384 + n0;
        char* base = smem + buf * BUFSZ;
        constexpr int NCHK = FULLB ? 8 : 6;
        #pragma unroll
        for (int i = 0; i < NCHK; ++i) {
            const int tile = i >> 1;                 // 0 Ah,1 Al,2 Bh,3 Bl
            const int r16  = ((i & 1) << 2) | w;     // 0..7
            char* dst = base + tile * 8192 + r16 * 1024;
            const char* src;
            if (tile == 0)
                src = (const char*)Ahp + ((arow0 + r16 * 16 + lrow) << 6) + (lquad << 4);
            else if (tile == 1)
                src = (const char*)Alp + ((arow0 + r16 * 16 + lrow) << 6) + (lquad << 4);
            else if (tile == 2)
                src = (const char*)Bhp + ((brow0 + r16 * 16 + lrow) << 6) + (lquad << 4);
            else
                src = (const char*)Blp + ((brow0 + r16 * 16 + lrow) << 6) + (lquad << 4);
            GLOAD16(src, dst);
        }
    };

    stage(0, 0);
    __syncthreads();

    #pragma unroll
    for (int s = 0; s < 8; ++s) {
        char* base = smem + (s & 1) * BUFSZ;
        if (s < 7) stage((s + 1) & 1, s + 1);   // prefetch next slice (other buf)

        bf16x8 ah[4], al[4], bh[4], bl[4];
        #pragma unroll
        for (int f = 0; f < 4; ++f) {
            const int aoff = (mh * 64 + f * 16) * 64 + swz;
            ah[f] = *(const bf16x8*)(base + aoff);
            al[f] = *(const bf16x8*)(base + 8192 + aoff);
            const int boff = (nh * 64 + f * 16) * 64 + swz;
            bh[f] = *(const bf16x8*)(base + 16384 + boff);
            if (FULLB) bl[f] = *(const bf16x8*)(base + 24576 + boff);
        }

        #pragma unroll
        for (int fm = 0; fm < 4; ++fm)
            #pragma unroll
            for (int fn = 0; fn < 4; ++fn) {
                acc[fm][fn] = __builtin_amdgcn_mfma_f32_16x16x32_bf16(ah[fm], bh[fn], acc[fm][fn], 0, 0, 0);
                if (FULLB)
                    acc[fm][fn] = __builtin_amdgcn_mfma_f32_16x16x32_bf16(ah[fm], bl[fn], acc[fm][fn], 0, 0, 0);
                acc[fm][fn] = __builtin_amdgcn_mfma_f32_16x16x32_bf16(al[fm], bh[fn], acc[fm][fn], 0, 0, 0);
            }

        if (s < 7) __syncthreads();
    }

    // epilogue: C/D layout col=lane&15, row=(lane>>4)*4+reg (m89)
    #pragma unroll
    for (int fm = 0; fm < 4; ++fm) {
        const int mrow0 = m0 + mh * 64 + fm * 16 + ((lane >> 4) << 2);
        #pragma unroll
        for (int fn = 0; fn < 4; ++fn) {
            const int ncol = n0 + nh * 64 + fn * 16 + (lane & 15);
            if (OUTBF16) {
                u16* Cb = (u16*)Cp + (size_t)bz * cBatch;
                #pragma unroll
                for (int r = 0; r < 4; ++r)
                    Cb[(size_t)(mrow0 + r) * HW + ncol] = f2bf(acc[fm][fn][r]);
            } else {
                float* Cb = (float*)Cp + (size_t)bz * cBatch;
                #pragma unroll
                for (int r = 0; r < 4; ++r)
                    Cb[(size_t)(mrow0 + r) * HW + ncol] = acc[fm][fn][r];
            }
        }
    }
}

// ---------------------------------------------------------------------------
// K2 (merged): depthwise 3x3 SAME for all 768 channels, bf16 in/out.
// Blocks [0,1024): v channels -> vth (fused transpose, quad-swizzled).
// Blocks [1024,5120): q,k channels -> dwb planes. Halo via __shfl.
// ---------------------------------------------------------------------------
__global__ __launch_bounds__(256)
void dwconv_all(const u16* __restrict__ qkvb, const float* __restrict__ wdw,
                u16* __restrict__ dwb, u16* __restrict__ vth)
{
    __shared__ u16 Lout[256][40];    // v path only; [n-local][ch], stride 40 u16
    const int bid = blockIdx.x;
    const int t = threadIdx.x;

    if (bid < 1024) {
        // ---------------- v path (fused transpose + swizzle) ----------------
        const int rp = bid & 63;         // rows 2rp, 2rp+1
        const int s  = (bid >> 6) & 7;
        const int bz = bid >> 9;
        const int ch = t >> 3;           // 0..31
        const int cg = t & 7;            // 16-col strip
        const int r0 = rp * 2;
        const int c0 = cg * 16;
        const int chg = 512 + s * 32 + ch;
        const u16* plane = qkvb + ((size_t)bz * NCH + chg) * HW;
        const float* wp = wdw + chg * 9;
        float w[9];
        #pragma unroll
        for (int i = 0; i < 9; ++i) w[i] = wp[i];

        float rv[4][18];
        #pragma unroll
        for (int j = 0; j < 4; ++j) {
            const int ry = r0 - 1 + j;
            if (ry < 0 || ry >= IMGW) {
                #pragma unroll
                for (int k = 0; k < 18; ++k) rv[j][k] = 0.f;
            } else {
                const u16* rw = plane + ry * IMGW;
                bf16x8 v0 = *(const bf16x8*)(rw + c0);
                bf16x8 v1 = *(const bf16x8*)(rw + c0 + 8);
                u32 lw = (u32)__shfl_up((int)(u16)v1[7], 1);   // lane-1 last col
                u32 rr = (u32)__shfl_down((int)(u16)v0[0], 1); // lane+1 first col
                rv[j][0] = (c0 > 0) ? bf2f((u16)lw) : 0.f;
                #pragma unroll
                for (int e = 0; e < 8; ++e) {
                    rv[j][1 + e] = bf2f((u16)v0[e]);
                    rv[j][9 + e] = bf2f((u16)v1[e]);
                }
                rv[j][17] = (c0 < 112) ? bf2f((u16)rr) : 0.f;
            }
        }

        #pragma unroll
        for (int rr2 = 0; rr2 < 2; ++rr2) {
            float acc[16];
            #pragma unroll
            for (int q = 0; q < 16; ++q) acc[q] = 0.f;
            #pragma unroll
            for (int dy = 0; dy < 3; ++dy)
                #pragma unroll
                for (int dx = 0; dx < 3; ++dx) {
                    float wv = w[dy * 3 + dx];
                    #pragma unroll
                    for (int q = 0; q < 16; ++q)
                        acc[q] = fmaf(rv[rr2 + dy][q + dx], wv, acc[q]);
                }
            #pragma unroll
            for (int q = 0; q < 16; ++q)
                Lout[rr2 * 128 + c0 + q][ch] = f2bf(acc[q]);
        }
        __syncthreads();

        u16* dst = vth + (((size_t)(bz * 8 + s)) * 16384 + rp * 256 + t) * 32;
        const int pq = (t >> 1) & 3;
        #pragma unroll
        for (int u = 0; u < 4; ++u)
            *(uint4*)(dst + u * 8) = *(const uint4*)(&Lout[t][(u ^ pq) * 8]);
    } else {
        // ---------------- q,k path ----------------
        const int qid = bid - 1024;
        const int y  = qid >> 2;            // 0..1023
        const int bi = y >> 9, ch = y & 511;
        const size_t p = (size_t)bi * NCH + ch;
        const int r0 = (qid & 3) * 32 + (t >> 5) * 4;
        const int c0 = (t & 31) << 2;

        const u16* plane = qkvb + p * HW;
        const float* wp = wdw + ch * 9;
        float w[9];
        #pragma unroll
        for (int i = 0; i < 9; ++i) w[i] = wp[i];

        float rv[6][6];
        #pragma unroll
        for (int j = 0; j < 6; ++j) {
            const int ry = r0 - 1 + j;
            if (ry < 0 || ry >= IMGW) {
                #pragma unroll
                for (int k = 0; k < 6; ++k) rv[j][k] = 0.f;
            } else {
                const u16* rp_ = plane + ry * IMGW;
                ushort4 vm = *(const ushort4*)(rp_ + c0);
                u32 lw = (u32)__shfl_up((int)vm.w, 1);
                u32 rr = (u32)__shfl_down((int)vm.x, 1);
                rv[j][0] = (c0 > 0)   ? bf2f((u16)lw) : 0.f;
                rv[j][1] = bf2f(vm.x); rv[j][2] = bf2f(vm.y);
                rv[j][3] = bf2f(vm.z); rv[j][4] = bf2f(vm.w);
                rv[j][5] = (c0 < 124) ? bf2f((u16)rr) : 0.f;
            }
        }

        #pragma unroll
        for (int rr2 = 0; rr2 < 4; ++rr2) {
            float acc[4] = {0.f, 0.f, 0.f, 0.f};
            #pragma unroll
            for (int dy = 0; dy < 3; ++dy) {
                #pragma unroll
                for (int dx = 0; dx < 3; ++dx) {
                    float wv = w[dy * 3 + dx];
                    #pragma unroll
                    for (int q = 0; q < 4; ++q)
                        acc[q] = fmaf(rv[rr2 + dy][q + dx], wv, acc[q]);
                }
            }
            ushort4 o4;
            o4.x = f2bf(acc[0]); o4.y = f2bf(acc[1]);
            o4.z = f2bf(acc[2]); o4.w = f2bf(acc[3]);
            *(ushort4*)(dwb + p * HW + (r0 + rr2) * IMGW + c0) = o4;
        }
    }
}

// ---------------------------------------------------------------------------
// K4: Gram via MFMA, fragments direct from global. grid (32 chunks, 16 bh).
// Sumsq (l2norm) folded in. part: [chunk][bh][32*32]; sumsqp: [chunk][bh][64]
// ---------------------------------------------------------------------------
__global__ __launch_bounds__(256)
void gram_mfma(const u16* __restrict__ dw, float* __restrict__ part,
               float* __restrict__ sumsqp)
{
    __shared__ float pl[4][32][32];
    __shared__ float sl[4][64];
    const int chunk = blockIdx.x;    // 0..31
    const int bh    = blockIdx.y;
    const int bi = bh >> 3, h = bh & 7;
    const u16* qbase = dw + ((size_t)bi * NCH + h * CPH) * HW;
    const u16* kbase = dw + ((size_t)bi * NCH + 256 + h * CPH) * HW;
    const int t = threadIdx.x, lane = t & 63, w = t >> 6;
    const int lr = lane & 15;
    const int lg = lane >> 4;

    f32x4 acc[2][2];
    #pragma unroll
    for (int i = 0; i < 2; ++i)
        #pragma unroll
        for (int j = 0; j < 2; ++j)
            acc[i][j] = (f32x4){0.f, 0.f, 0.f, 0.f};
    float sq[4] = {0.f, 0.f, 0.f, 0.f};

    #pragma unroll
    for (int ks = 0; ks < 4; ++ks) {
        const int nb = chunk * 512 + w * 128 + ks * 32 + lg * 8;
        bf16x8 a0 = *(const bf16x8*)(qbase + (size_t)lr * HW + nb);
        bf16x8 a1 = *(const bf16x8*)(qbase + (size_t)(lr + 16) * HW + nb);
        bf16x8 b0 = *(const bf16x8*)(kbase + (size_t)lr * HW + nb);
        bf16x8 b1 = *(const bf16x8*)(kbase + (size_t)(lr + 16) * HW + nb);
        acc[0][0] = __builtin_amdgcn_mfma_f32_16x16x32_bf16(a0, b0, acc[0][0], 0, 0, 0);
        acc[0][1] = __builtin_amdgcn_mfma_f32_16x16x32_bf16(a0, b1, acc[0][1], 0, 0, 0);
        acc[1][0] = __builtin_amdgcn_mfma_f32_16x16x32_bf16(a1, b0, acc[1][0], 0, 0, 0);
        acc[1][1] = __builtin_amdgcn_mfma_f32_16x16x32_bf16(a1, b1, acc[1][1], 0, 0, 0);
        #pragma unroll
        for (int e = 0; e < 8; ++e) {
            float f0 = bf2f((u16)a0[e]); sq[0] = fmaf(f0, f0, sq[0]);
            float f1 = bf2f((u16)a1[e]); sq[1] = fmaf(f1, f1, sq[1]);
            float f2 = bf2f((u16)b0[e]); sq[2] = fmaf(f2, f2, sq[2]);
            float f3 = bf2f((u16)b1[e]); sq[3] = fmaf(f3, f3, sq[3]);
        }
    }
    #pragma unroll
    for (int i = 0; i < 4; ++i) {
        sq[i] += __shfl_xor(sq[i], 16);
        sq[i] += __shfl_xor(sq[i], 32);
    }
    if (lane < 16) {
        sl[w][lane]      = sq[0];
        sl[w][16 + lane] = sq[1];
        sl[w][32 + lane] = sq[2];
        sl[w][48 + lane] = sq[3];
    }
    #pragma unroll
    for (int qt = 0; qt < 2; ++qt)
        #pragma unroll
        for (int kt = 0; kt < 2; ++kt)
            #pragma unroll
            for (int r = 0; r < 4; ++r)
                pl[w][qt * 16 + lg * 4 + r][kt * 16 + lr] = acc[qt][kt][r];
    __syncthreads();

    #pragma unroll
    for (int i = 0; i < 4; ++i) {
        const int o = i * 256 + t;
        const int qc = o >> 5, kd = o & 31;
        float s = pl[0][qc][kd] + pl[1][qc][kd] + pl[2][qc][kd] + pl[3][qc][kd];
        part[((size_t)chunk * 16 + bh) * 1024 + o] = s;
    }
    if (t < 64) {
        float s = sl[0][t] + sl[1][t] + sl[2][t] + sl[3][t];
        sumsqp[((size_t)chunk * 16 + bh) * 64 + t] = s;
    }
}

// ---------------------------------------------------------------------------
// K5a: reduce partials + apply inv norms and temperature -> attn
// ---------------------------------------------------------------------------
__global__ __launch_bounds__(256)
void gram_finish(const float* __restrict__ part, const float* __restrict__ sumsqp,
                 const float* __restrict__ temp, float* __restrict__ attn)
{
    const int idx = blockIdx.x * 256 + threadIdx.x;  // 0..16383
    const int bh = idx >> 10;
    const int h = bh & 7;
    const int c = (idx >> 5) & 31, d = idx & 31;
    float s = 0.f, sqq = 0.f, sqk = 0.f;
    #pragma unroll
    for (int ch = 0; ch < 32; ++ch) {
        s   += part[(size_t)ch * 16384 + idx];
        sqq += sumsqp[((size_t)ch * 16 + bh) * 64 + c];
        sqk += sumsqp[((size_t)ch * 16 + bh) * 64 + 32 + d];
    }
    float iq = 1.f / fmaxf(sqrtf(sqq), 1e-12f);
    float ik = 1.f / fmaxf(sqrtf(sqk), 1e-12f);
    attn[idx] = s * iq * ik * temp[h];
}

// ---------------------------------------------------------------------------
// K5b: rank counting, parallelized. grid (8 seg, 16 bh), 128 threads.
// ---------------------------------------------------------------------------
__global__ __launch_bounds__(128)
void rank4(const float* __restrict__ attn, float* __restrict__ vthr_g)
{
    __shared__ float xs[1024];
    const int seg = blockIdx.x, bh = blockIdx.y;
    const int t = threadIdx.x;
    const float* row = attn + bh * 1024;

    *(float4*)(&xs[t * 8])     = *(const float4*)(row + t * 8);
    *(float4*)(&xs[t * 8 + 4]) = *(const float4*)(row + t * 8 + 4);
    __syncthreads();

    const float x = xs[seg * 128 + t];
    int g = 0, e = 0;
    const float4* xs4 = (const float4*)xs;
    for (int j = 0; j < 256; ++j) {
        float4 v = xs4[j];
        g += (v.x > x) + (v.y > x) + (v.z > x) + (v.w > x);
        e += (v.x == x) + (v.y == x) + (v.z == x) + (v.w == x);
    }
    if (g == 0) vthr_g[bh * 8 + 4] = x;              // the max
    const int topks[4] = {512, 682, 768, 819};
    #pragma unroll
    for (int kk = 0; kk < 4; ++kk)
        if (g <= topks[kk] - 1 && topks[kk] - 1 < g + e) vthr_g[bh * 8 + kk] = x;
}

// ---------------------------------------------------------------------------
// K5c+K6 merged (soft_m2): one block (1024 thr) per bh.
// Phase 1: exp + 4 masked sums (identical reduction order as apply_soft),
//   spar row kept in LDS (no global round trip).
// Phase 2: M2[b][o][h*32+d] = sum_cc Wproj[o][h*32+cc]*spar[cc][d], emitted
//   as split bf16 in the quad-swizzled MFMA A-layout (identical to build_m2:
//   cc-ascending FMA order -> bit-exact).
// ---------------------------------------------------------------------------
__global__ __launch_bounds__(1024)
void soft_m2(const float* __restrict__ attn, const float* __restrict__ vthr_g,
             const float* __restrict__ wproj,
             u16* __restrict__ m2h, u16* __restrict__ m2l,
             const float* __restrict__ a1, const float* __restrict__ a2,
             const float* __restrict__ a3, const float* __restrict__ a4)
{
    __shared__ float red[16 * 4];
    __shared__ float ssh[4];
    __shared__ float sps[1024];      // spar row for this bh
    const int bh = blockIdx.x, t = threadIdx.x;
    const int b = bh >> 3, h = bh & 7;
    const float x = attn[bh * 1024 + t];
    float vthr[4];
    #pragma unroll
    for (int kk = 0; kk < 4; ++kk) vthr[kk] = vthr_g[bh * 8 + kk];
    const float m = vthr_g[bh * 8 + 4];

    float ex = expf(x - m);
    float v4[4];
    #pragma unroll
    for (int kk = 0; kk < 4; ++kk) v4[kk] = (x >= vthr[kk]) ? ex : 0.f;
    #pragma unroll
    for (int off = 32; off; off >>= 1)
        #pragma unroll
        for (int kk = 0; kk < 4; ++kk) v4[kk] += __shfl_down(v4[kk], off);
    const int lane = t & 63, wid = t >> 6;
    if (lane == 0) {
        #pragma unroll
        for (int kk = 0; kk < 4; ++kk) red[wid * 4 + kk] = v4[kk];
    }
    __syncthreads();
    if (t == 0) {
        float s0 = 0, s1 = 0, s2 = 0, s3 = 0;
        for (int ww = 0; ww < 16; ++ww) {
            s0 += red[ww * 4 + 0]; s1 += red[ww * 4 + 1];
            s2 += red[ww * 4 + 2]; s3 += red[ww * 4 + 3];
        }
        ssh[0] = s0; ssh[1] = s1; ssh[2] = s2; ssh[3] = s3;
    }
    __syncthreads();

    float av[4] = {*a1, *a2, *a3, *a4};
    float coef = 0.f;
    #pragma unroll
    for (int kk = 0; kk < 4; ++kk)
        if (x >= vthr[kk]) coef += av[kk] / ssh[kk];
    sps[t] = ex * coef;
    __syncthreads();

    // ---- M2 phase: o = t>>2 (0..255), dq = t&3 (d-quad), 8 d each ----
    const int o = t >> 2, dq = t & 3;
    const float* wrow = wproj + o * 256 + h * CPH;
    u32 hq[4], lq[4];
    #pragma unroll
    for (int e2 = 0; e2 < 4; ++e2) {
        u32 hw2 = 0, lw2 = 0;
        #pragma unroll
        for (int half = 0; half < 2; ++half) {
            const int d = dq * 8 + e2 * 2 + half;
            float acc = 0.f;
            #pragma unroll 8
            for (int cc = 0; cc < 32; ++cc)
                acc = fmaf(wrow[cc], sps[cc * 32 + d], acc);
            u16 hi = f2bf(acc);
            u16 lo = f2bf(acc - bf2f(hi));
            hw2 |= (u32)hi << (16 * half);
            lw2 |= (u32)lo << (16 * half);
        }
        hq[e2] = hw2; lq[e2] = lw2;
    }
    const int p = (o >> 1) & 3;
    size_t base = ((size_t)(b * 2048 + h * 256 + o)) << 5;
    uint4 hv = {hq[0], hq[1], hq[2], hq[3]};
    uint4 lv = {lq[0], lq[1], lq[2], lq[3]};
    *(uint4*)(m2h + base + ((dq ^ p) << 3)) = hv;
    *(uint4*)(m2l + base + ((dq ^ p) << 3)) = lv;
}

// ---------------------------------------------------------------------------
// launch
// ---------------------------------------------------------------------------
extern "C" void kernel_launch(void* const* d_in, const int* in_sizes, int n_in,
                              void* d_out, int out_size, void* d_ws, size_t ws_size,
                              hipStream_t stream)
{
    const float* x      = (const float*)d_in[0];
    const float* w_qkv  = (const float*)d_in[1];
    const float* w_dw   = (const float*)d_in[2];
    const float* w_proj = (const float*)d_in[3];
    const float* temp   = (const float*)d_in[4];
    const float* a1     = (const float*)d_in[5];
    const float* a2     = (const float*)d_in[6];
    const float* a3     = (const float*)d_in[7];
    const float* a4     = (const float*)d_in[8];

    float* ws = (float*)d_ws;
    u16* qkvb = (u16*)ws;
    u16* vth  = (u16*)(ws + 12582912);
    float* sumsqp = ws;                      // 32*16*64 = 32768 floats
    float* part   = ws + 32768;              // 32*16*1024 = 524288 floats
    float* attn   = ws + 557056;             // 16384 floats
    float* vthr_g = ws + 573440;             // 16*8 = 128 floats
    u16* m2h = (u16*)(ws + 573568);          // 131072 u16
    u16* m2l = m2h + 131072;                 // 131072 u16
    float* r1 = ws + (size_t)25165824;
    u16* xth = (u16*)r1;                     // 8388608 u16
    u16* xtl = xth + (size_t)8388608;
    u16* whp = xtl + (size_t)8388608;        // 196608 u16
    u16* wlp = whp + (size_t)196608;
    u16* dwb = (u16*)r1;                     // [2][768][HW] bf16 (after K1')

    // T1+T2 merged: split W + transpose/split x (quad-swizzled)
    prep_inputs<<<2072, 256, 0, stream>>>(x, w_qkv, xth, xtl, whp, wlp);
    // K1': qkv = W_qkv @ x (LDS 2-phase split MFMA, XCD swizzle, bf16 out)
    gemm_mfma_split<true, true, 6><<<1536, 256, 0, stream>>>(
        whp, wlp, xth, xtl, qkvb, 0, 768, (long)NCH * HW);
    // K2: depthwise 3x3, merged: v -> vth (fused transpose) + q,k -> dwb
    dwconv_all<<<5120, 256, 0, stream>>>(qkvb, w_dw, dwb, vth);
    // K4: Gram via direct MFMA + fused sumsq
    gram_mfma<<<dim3(32, 16), 256, 0, stream>>>(dwb, part, sumsqp);
    // K5: finish -> rank (parallel) -> softmax+M2 (merged)
    gram_finish<<<64, 256, 0, stream>>>(part, sumsqp, temp, attn);
    rank4<<<dim3(8, 16), 128, 0, stream>>>(attn, vthr_g);
    soft_m2<<<16, 1024, 0, stream>>>(attn, vthr_g, w_proj, m2h, m2l, a1, a2, a3, a4);
    // K7': out = M2 @ v (LDS 2-phase 2-product MFMA, fp32 out)
    gemm_mfma_split<false, false, 2><<<512, 256, 0, stream>>>(
        m2h, m2l, vth, nullptr, d_out, 2048, 256, (long)DIMC * HW);
}

// Round 16
// 122.721 us; speedup vs baseline: 1.0434x; 1.0434x over previous
//
#include <hip/hip_runtime.h>
#include <stdint.h>

// Problem geometry (fixed)
#define HW     16384      // 128*128
#define IMGW   128
#define NCH    768        // 3*DIM
#define DIMC   256
#define NB     2
#define CPH    32         // channels per head

typedef unsigned short u16;
typedef unsigned int   u32;
typedef __attribute__((ext_vector_type(8))) short bf16x8;
typedef __attribute__((ext_vector_type(4))) float f32x4;

__device__ __forceinline__ float bf2f(u16 u) { return __uint_as_float(((u32)u) << 16); }
__device__ __forceinline__ u16 f2bf(float f) {
    u32 u = __float_as_uint(f);
    u += 0x7fffu + ((u >> 16) & 1u);
    return (u16)(u >> 16);
}

#define GLOAD16(gp, lp) __builtin_amdgcn_global_load_lds( \
    (const __attribute__((address_space(1))) void*)(gp),  \
    (__attribute__((address_space(3))) void*)(lp), 16, 0, 0)

// ---------------------------------------------------------------------------
// T1+T2 merged (prep_inputs):
// blocks [0,2048): transpose + split x (fp32) -> xT hi/lo bf16,
//   layout [b*8+s][16384 n][32 c], quad-swizzled (slot u holds quad u^((n>>1)&3))
// blocks [2048,2072): split W_qkv -> hi/lo bf16, layout [s=8][768 m][32 c],
//   quad-swizzled (slot u holds quad u^((m>>1)&3))
// ---------------------------------------------------------------------------
__global__ __launch_bounds__(256)
void prep_inputs(const float* __restrict__ x, const float* __restrict__ w,
                 u16* __restrict__ xth, u16* __restrict__ xtl,
                 u16* __restrict__ wh, u16* __restrict__ wl)
{
    __shared__ float Xs[64][68];
    const int bid = blockIdx.x;
    const int t = threadIdx.x;

    if (bid < 2048) {
        const int bz = bid >> 10;
        const int r  = bid & 1023;
        const int nt = r & 255;
        const int ct = r >> 8;
        const int n0 = nt * 64, c0 = ct * 64;
        const float* xb = x + (size_t)bz * DIMC * HW;

        #pragma unroll
        for (int it = 0; it < 4; ++it) {
            int cl = (t >> 4) + it * 16;
            int nl4 = (t & 15) << 2;
            float4 v = *(const float4*)(xb + (size_t)(c0 + cl) * HW + n0 + nl4);
            Xs[cl][nl4]     = v.x; Xs[cl][nl4 + 1] = v.y;
            Xs[cl][nl4 + 2] = v.z; Xs[cl][nl4 + 3] = v.w;
        }
        __syncthreads();

        const int nl = t >> 2, u = t & 3;
        const int p = (nl >> 1) & 3;                  // n0 is mult of 64
        #pragma unroll
        for (int sl = 0; sl < 2; ++sl) {
            const int s = (c0 >> 5) + sl;
            const int cb = sl * 32 + ((u ^ p) << 3);
            u32 hq[4], lq[4];
            #pragma unroll
            for (int e2 = 0; e2 < 4; ++e2) {
                float f0 = Xs[cb + 2 * e2][nl];
                float f1 = Xs[cb + 2 * e2 + 1][nl];
                u16 h0 = f2bf(f0); u16 l0 = f2bf(f0 - bf2f(h0));
                u16 h1 = f2bf(f1); u16 l1 = f2bf(f1 - bf2f(h1));
                hq[e2] = (u32)h0 | ((u32)h1 << 16);
                lq[e2] = (u32)l0 | ((u32)l1 << 16);
            }
            size_t rowb = ((size_t)((bz * 8 + s)) * 16384 + n0 + nl) << 6;
            uint4 hv = {hq[0], hq[1], hq[2], hq[3]};
            uint4 lv = {lq[0], lq[1], lq[2], lq[3]};
            *(uint4*)((char*)xth + rowb + (u << 4)) = hv;
            *(uint4*)((char*)xtl + rowb + (u << 4)) = lv;
        }
    } else {
        const int idx = (bid - 2048) * 256 + t;   // 0..6143
        const int m = idx >> 3, s = idx & 7;
        const int p = (m >> 1) & 3;
        #pragma unroll
        for (int u = 0; u < 4; ++u) {
            const int cb = s * 32 + ((u ^ p) << 3);
            u32 hq[4], lq[4];
            #pragma unroll
            for (int e2 = 0; e2 < 4; ++e2) {
                float f0 = w[m * 256 + cb + 2 * e2];
                float f1 = w[m * 256 + cb + 2 * e2 + 1];
                u16 h0 = f2bf(f0); u16 l0 = f2bf(f0 - bf2f(h0));
                u16 h1 = f2bf(f1); u16 l1 = f2bf(f1 - bf2f(h1));
                hq[e2] = (u32)h0 | ((u32)h1 << 16);
                lq[e2] = (u32)l0 | ((u32)l1 << 16);
            }
            size_t rowb = ((size_t)(s * 768 + m)) << 6;   // 64 B per row
            uint4 hv = {hq[0], hq[1], hq[2], hq[3]};
            uint4 lv = {lq[0], lq[1], lq[2], lq[3]};
            *(uint4*)((char*)wh + rowb + (u << 4)) = hv;
            *(uint4*)((char*)wl + rowb + (u << 4)) = lv;
        }
    }
}

// ---------------------------------------------------------------------------
// K1'/K7': C[bz][m][n] = sum_c A[m][c] * B[bz][c][n] via split-bf16 MFMA.
// LDS 2-phase double-buffered pipeline (stage s+1 before compute s) +
// XCD-chunked block swizzle. Quad-swizzled operand layouts -> conflict-free
// ds_read_b128. FULLB: B hi+lo (3 products). !FULLB: B hi only (2 products).
// ---------------------------------------------------------------------------
template<bool FULLB, bool OUTBF16, int MBLKS>
__global__ __launch_bounds__(256, 2)
void gemm_mfma_split(const u16* __restrict__ Ahp, const u16* __restrict__ Alp,
                     const u16* __restrict__ Bhp, const u16* __restrict__ Blp,
                     void* __restrict__ Cp, int aBatch, int aSlice, long cBatch)
{
    constexpr int BUFSZ = FULLB ? 32768 : 24576;  // {Ah,Al,Bh[,Bl]} x 8KB
    __shared__ char smem[2 * BUFSZ];

    const int t    = threadIdx.x;
    const int lane = t & 63;
    const int w    = t >> 6;
    // XCD-chunked swizzle (nwg % 8 == 0)
    const int per = gridDim.x >> 3;
    const int wid = (blockIdx.x & 7) * per + (blockIdx.x >> 3);
    const int nglob = wid / MBLKS;               // m iterates fastest
    const int m0 = (wid % MBLKS) * 128;
    const int bz = nglob >> 7;
    const int n0 = (nglob & 127) * 128;

    const int lrow  = lane >> 2;       // 0..15
    const int lquad = lane & 3;
    const int mh = w >> 1, nh = w & 1;
    const int swz = ((lane & 15) << 6) + ((((lane >> 4) ^ ((lane >> 1) & 3))) << 4);

    f32x4 acc[4][4];
    #pragma unroll
    for (int i = 0; i < 4; ++i)
        #pragma unroll
        for (int j = 0; j < 4; ++j)
            acc[i][j] = (f32x4){0.f, 0.f, 0.f, 0.f};

    auto stage = [&](int buf, int s) {
        const size_t arow0 = (size_t)bz * aBatch + (size_t)s * aSlice + m0;
        const size_t brow0 = ((size_t)(bz * 8 + s)) * 16384 + n0;
        char* base = smem + buf * BUFSZ;
        constexpr int NCHK = FULLB ? 8 : 6;
        #pragma unroll
        for (int i = 0; i < NCHK; ++i) {
            const int tile = i >> 1;                 // 0 Ah,1 Al,2 Bh,3 Bl
            const int r16  = ((i & 1) << 2) | w;     // 0..7
            char* dst = base + tile * 8192 + r16 * 1024;
            const char* src;
            if (tile == 0)
                src = (const char*)Ahp + ((arow0 + r16 * 16 + lrow) << 6) + (lquad << 4);
            else if (tile == 1)
                src = (const char*)Alp + ((arow0 + r16 * 16 + lrow) << 6) + (lquad << 4);
            else if (tile == 2)
                src = (const char*)Bhp + ((brow0 + r16 * 16 + lrow) << 6) + (lquad << 4);
            else
                src = (const char*)Blp + ((brow0 + r16 * 16 + lrow) << 6) + (lquad << 4);
            GLOAD16(src, dst);
        }
    };

    stage(0, 0);
    __syncthreads();

    #pragma unroll
    for (int s = 0; s < 8; ++s) {
        char* base = smem + (s & 1) * BUFSZ;
        if (s < 7) stage((s + 1) & 1, s + 1);   // prefetch next slice (other buf)

        bf16x8 ah[4], al[4], bh[4], bl[4];
        #pragma unroll
        for (int f = 0; f < 4; ++f) {
            const int aoff = (mh * 64 + f * 16) * 64 + swz;
            ah[f] = *(const bf16x8*)(base + aoff);
            al[f] = *(const bf16x8*)(base + 8192 + aoff);
            const int boff = (nh * 64 + f * 16) * 64 + swz;
            bh[f] = *(const bf16x8*)(base + 16384 + boff);
            if (FULLB) bl[f] = *(const bf16x8*)(base + 24576 + boff);
        }

        #pragma unroll
        for (int fm = 0; fm < 4; ++fm)
            #pragma unroll
            for (int fn = 0; fn < 4; ++fn) {
                acc[fm][fn] = __builtin_amdgcn_mfma_f32_16x16x32_bf16(ah[fm], bh[fn], acc[fm][fn], 0, 0, 0);
                if (FULLB)
                    acc[fm][fn] = __builtin_amdgcn_mfma_f32_16x16x32_bf16(ah[fm], bl[fn], acc[fm][fn], 0, 0, 0);
                acc[fm][fn] = __builtin_amdgcn_mfma_f32_16x16x32_bf16(al[fm], bh[fn], acc[fm][fn], 0, 0, 0);
            }

        if (s < 7) __syncthreads();
    }

    // epilogue: C/D layout col=lane&15, row=(lane>>4)*4+reg (m89)
    #pragma unroll
    for (int fm = 0; fm < 4; ++fm) {
        const int mrow0 = m0 + mh * 64 + fm * 16 + ((lane >> 4) << 2);
        #pragma unroll
        for (int fn = 0; fn < 4; ++fn) {
            const int ncol = n0 + nh * 64 + fn * 16 + (lane & 15);
            if (OUTBF16) {
                u16* Cb = (u16*)Cp + (size_t)bz * cBatch;
                #pragma unroll
                for (int r = 0; r < 4; ++r)
                    Cb[(size_t)(mrow0 + r) * HW + ncol] = f2bf(acc[fm][fn][r]);
            } else {
                float* Cb = (float*)Cp + (size_t)bz * cBatch;
                #pragma unroll
                for (int r = 0; r < 4; ++r)
                    Cb[(size_t)(mrow0 + r) * HW + ncol] = acc[fm][fn][r];
            }
        }
    }
}

// ---------------------------------------------------------------------------
// K2 (merged): depthwise 3x3 SAME for all 768 channels, bf16 in/out.
// Blocks [0,1024): v channels -> vth (fused transpose, quad-swizzled).
// Blocks [1024,5120): q,k channels -> dwb planes. Halo via __shfl.
// ---------------------------------------------------------------------------
__global__ __launch_bounds__(256)
void dwconv_all(const u16* __restrict__ qkvb, const float* __restrict__ wdw,
                u16* __restrict__ dwb, u16* __restrict__ vth)
{
    __shared__ u16 Lout[256][40];    // v path only; [n-local][ch], stride 40 u16
    const int bid = blockIdx.x;
    const int t = threadIdx.x;

    if (bid < 1024) {
        // ---------------- v path (fused transpose + swizzle) ----------------
        const int rp = bid & 63;         // rows 2rp, 2rp+1
        const int s  = (bid >> 6) & 7;
        const int bz = bid >> 9;
        const int ch = t >> 3;           // 0..31
        const int cg = t & 7;            // 16-col strip
        const int r0 = rp * 2;
        const int c0 = cg * 16;
        const int chg = 512 + s * 32 + ch;
        const u16* plane = qkvb + ((size_t)bz * NCH + chg) * HW;
        const float* wp = wdw + chg * 9;
        float w[9];
        #pragma unroll
        for (int i = 0; i < 9; ++i) w[i] = wp[i];

        float rv[4][18];
        #pragma unroll
        for (int j = 0; j < 4; ++j) {
            const int ry = r0 - 1 + j;
            if (ry < 0 || ry >= IMGW) {
                #pragma unroll
                for (int k = 0; k < 18; ++k) rv[j][k] = 0.f;
            } else {
                const u16* rw = plane + ry * IMGW;
                bf16x8 v0 = *(const bf16x8*)(rw + c0);
                bf16x8 v1 = *(const bf16x8*)(rw + c0 + 8);
                u32 lw = (u32)__shfl_up((int)(u16)v1[7], 1);   // lane-1 last col
                u32 rr = (u32)__shfl_down((int)(u16)v0[0], 1); // lane+1 first col
                rv[j][0] = (c0 > 0) ? bf2f((u16)lw) : 0.f;
                #pragma unroll
                for (int e = 0; e < 8; ++e) {
                    rv[j][1 + e] = bf2f((u16)v0[e]);
                    rv[j][9 + e] = bf2f((u16)v1[e]);
                }
                rv[j][17] = (c0 < 112) ? bf2f((u16)rr) : 0.f;
            }
        }

        #pragma unroll
        for (int rr2 = 0; rr2 < 2; ++rr2) {
            float acc[16];
            #pragma unroll
            for (int q = 0; q < 16; ++q) acc[q] = 0.f;
            #pragma unroll
            for (int dy = 0; dy < 3; ++dy)
                #pragma unroll
                for (int dx = 0; dx < 3; ++dx) {
                    float wv = w[dy * 3 + dx];
                    #pragma unroll
                    for (int q = 0; q < 16; ++q)
                        acc[q] = fmaf(rv[rr2 + dy][q + dx], wv, acc[q]);
                }
            #pragma unroll
            for (int q = 0; q < 16; ++q)
                Lout[rr2 * 128 + c0 + q][ch] = f2bf(acc[q]);
        }
        __syncthreads();

        u16* dst = vth + (((size_t)(bz * 8 + s)) * 16384 + rp * 256 + t) * 32;
        const int pq = (t >> 1) & 3;
        #pragma unroll
        for (int u = 0; u < 4; ++u)
            *(uint4*)(dst + u * 8) = *(const uint4*)(&Lout[t][(u ^ pq) * 8]);
    } else {
        // ---------------- q,k path ----------------
        const int qid = bid - 1024;
        const int y  = qid >> 2;            // 0..1023
        const int bi = y >> 9, ch = y & 511;
        const size_t p = (size_t)bi * NCH + ch;
        const int r0 = (qid & 3) * 32 + (t >> 5) * 4;
        const int c0 = (t & 31) << 2;

        const u16* plane = qkvb + p * HW;
        const float* wp = wdw + ch * 9;
        float w[9];
        #pragma unroll
        for (int i = 0; i < 9; ++i) w[i] = wp[i];

        float rv[6][6];
        #pragma unroll
        for (int j = 0; j < 6; ++j) {
            const int ry = r0 - 1 + j;
            if (ry < 0 || ry >= IMGW) {
                #pragma unroll
                for (int k = 0; k < 6; ++k) rv[j][k] = 0.f;
            } else {
                const u16* rp_ = plane + ry * IMGW;
                ushort4 vm = *(const ushort4*)(rp_ + c0);
                u32 lw = (u32)__shfl_up((int)vm.w, 1);
                u32 rr = (u32)__shfl_down((int)vm.x, 1);
                rv[j][0] = (c0 > 0)   ? bf2f((u16)lw) : 0.f;
                rv[j][1] = bf2f(vm.x); rv[j][2] = bf2f(vm.y);
                rv[j][3] = bf2f(vm.z); rv[j][4] = bf2f(vm.w);
                rv[j][5] = (c0 < 124) ? bf2f((u16)rr) : 0.f;
            }
        }

        #pragma unroll
        for (int rr2 = 0; rr2 < 4; ++rr2) {
            float acc[4] = {0.f, 0.f, 0.f, 0.f};
            #pragma unroll
            for (int dy = 0; dy < 3; ++dy) {
                #pragma unroll
                for (int dx = 0; dx < 3; ++dx) {
                    float wv = w[dy * 3 + dx];
                    #pragma unroll
                    for (int q = 0; q < 4; ++q)
                        acc[q] = fmaf(rv[rr2 + dy][q + dx], wv, acc[q]);
                }
            }
            ushort4 o4;
            o4.x = f2bf(acc[0]); o4.y = f2bf(acc[1]);
            o4.z = f2bf(acc[2]); o4.w = f2bf(acc[3]);
            *(ushort4*)(dwb + p * HW + (r0 + rr2) * IMGW + c0) = o4;
        }
    }
}

// ---------------------------------------------------------------------------
// K4: Gram via MFMA, fragments direct from global. grid (32 chunks, 16 bh).
// Sumsq (l2norm) folded in. part: [chunk][bh][32*32]; sumsqp: [chunk][bh][64]
// ---------------------------------------------------------------------------
__global__ __launch_bounds__(256)
void gram_mfma(const u16* __restrict__ dw, float* __restrict__ part,
               float* __restrict__ sumsqp)
{
    __shared__ float pl[4][32][32];
    __shared__ float sl[4][64];
    const int chunk = blockIdx.x;    // 0..31
    const int bh    = blockIdx.y;
    const int bi = bh >> 3, h = bh & 7;
    const u16* qbase = dw + ((size_t)bi * NCH + h * CPH) * HW;
    const u16* kbase = dw + ((size_t)bi * NCH + 256 + h * CPH) * HW;
    const int t = threadIdx.x, lane = t & 63, w = t >> 6;
    const int lr = lane & 15;
    const int lg = lane >> 4;

    f32x4 acc[2][2];
    #pragma unroll
    for (int i = 0; i < 2; ++i)
        #pragma unroll
        for (int j = 0; j < 2; ++j)
            acc[i][j] = (f32x4){0.f, 0.f, 0.f, 0.f};
    float sq[4] = {0.f, 0.f, 0.f, 0.f};

    #pragma unroll
    for (int ks = 0; ks < 4; ++ks) {
        const int nb = chunk * 512 + w * 128 + ks * 32 + lg * 8;
        bf16x8 a0 = *(const bf16x8*)(qbase + (size_t)lr * HW + nb);
        bf16x8 a1 = *(const bf16x8*)(qbase + (size_t)(lr + 16) * HW + nb);
        bf16x8 b0 = *(const bf16x8*)(kbase + (size_t)lr * HW + nb);
        bf16x8 b1 = *(const bf16x8*)(kbase + (size_t)(lr + 16) * HW + nb);
        acc[0][0] = __builtin_amdgcn_mfma_f32_16x16x32_bf16(a0, b0, acc[0][0], 0, 0, 0);
        acc[0][1] = __builtin_amdgcn_mfma_f32_16x16x32_bf16(a0, b1, acc[0][1], 0, 0, 0);
        acc[1][0] = __builtin_amdgcn_mfma_f32_16x16x32_bf16(a1, b0, acc[1][0], 0, 0, 0);
        acc[1][1] = __builtin_amdgcn_mfma_f32_16x16x32_bf16(a1, b1, acc[1][1], 0, 0, 0);
        #pragma unroll
        for (int e = 0; e < 8; ++e) {
            float f0 = bf2f((u16)a0[e]); sq[0] = fmaf(f0, f0, sq[0]);
            float f1 = bf2f((u16)a1[e]); sq[1] = fmaf(f1, f1, sq[1]);
            float f2 = bf2f((u16)b0[e]); sq[2] = fmaf(f2, f2, sq[2]);
            float f3 = bf2f((u16)b1[e]); sq[3] = fmaf(f3, f3, sq[3]);
        }
    }
    #pragma unroll
    for (int i = 0; i < 4; ++i) {
        sq[i] += __shfl_xor(sq[i], 16);
        sq[i] += __shfl_xor(sq[i], 32);
    }
    if (lane < 16) {
        sl[w][lane]      = sq[0];
        sl[w][16 + lane] = sq[1];
        sl[w][32 + lane] = sq[2];
        sl[w][48 + lane] = sq[3];
    }
    #pragma unroll
    for (int qt = 0; qt < 2; ++qt)
        #pragma unroll
        for (int kt = 0; kt < 2; ++kt)
            #pragma unroll
            for (int r = 0; r < 4; ++r)
                pl[w][qt * 16 + lg * 4 + r][kt * 16 + lr] = acc[qt][kt][r];
    __syncthreads();

    #pragma unroll
    for (int i = 0; i < 4; ++i) {
        const int o = i * 256 + t;
        const int qc = o >> 5, kd = o & 31;
        float s = pl[0][qc][kd] + pl[1][qc][kd] + pl[2][qc][kd] + pl[3][qc][kd];
        part[((size_t)chunk * 16 + bh) * 1024 + o] = s;
    }
    if (t < 64) {
        float s = sl[0][t] + sl[1][t] + sl[2][t] + sl[3][t];
        sumsqp[((size_t)chunk * 16 + bh) * 64 + t] = s;
    }
}

// ---------------------------------------------------------------------------
// K5a: reduce partials + apply inv norms and temperature -> attn
// ---------------------------------------------------------------------------
__global__ __launch_bounds__(256)
void gram_finish(const float* __restrict__ part, const float* __restrict__ sumsqp,
                 const float* __restrict__ temp, float* __restrict__ attn)
{
    const int idx = blockIdx.x * 256 + threadIdx.x;  // 0..16383
    const int bh = idx >> 10;
    const int h = bh & 7;
    const int c = (idx >> 5) & 31, d = idx & 31;
    float s = 0.f, sqq = 0.f, sqk = 0.f;
    #pragma unroll
    for (int ch = 0; ch < 32; ++ch) {
        s   += part[(size_t)ch * 16384 + idx];
        sqq += sumsqp[((size_t)ch * 16 + bh) * 64 + c];
        sqk += sumsqp[((size_t)ch * 16 + bh) * 64 + 32 + d];
    }
    float iq = 1.f / fmaxf(sqrtf(sqq), 1e-12f);
    float ik = 1.f / fmaxf(sqrtf(sqk), 1e-12f);
    attn[idx] = s * iq * ik * temp[h];
}

// ---------------------------------------------------------------------------
// K5b: rank counting, parallelized. grid (8 seg, 16 bh), 128 threads.
// ---------------------------------------------------------------------------
__global__ __launch_bounds__(128)
void rank4(const float* __restrict__ attn, float* __restrict__ vthr_g)
{
    __shared__ float xs[1024];
    const int seg = blockIdx.x, bh = blockIdx.y;
    const int t = threadIdx.x;
    const float* row = attn + bh * 1024;

    *(float4*)(&xs[t * 8])     = *(const float4*)(row + t * 8);
    *(float4*)(&xs[t * 8 + 4]) = *(const float4*)(row + t * 8 + 4);
    __syncthreads();

    const float x = xs[seg * 128 + t];
    int g = 0, e = 0;
    const float4* xs4 = (const float4*)xs;
    for (int j = 0; j < 256; ++j) {
        float4 v = xs4[j];
        g += (v.x > x) + (v.y > x) + (v.z > x) + (v.w > x);
        e += (v.x == x) + (v.y == x) + (v.z == x) + (v.w == x);
    }
    if (g == 0) vthr_g[bh * 8 + 4] = x;              // the max
    const int topks[4] = {512, 682, 768, 819};
    #pragma unroll
    for (int kk = 0; kk < 4; ++kk)
        if (g <= topks[kk] - 1 && topks[kk] - 1 < g + e) vthr_g[bh * 8 + kk] = x;
}

// ---------------------------------------------------------------------------
// K5c: apply - exp, 4 masked sums (identical reduction order), write spar.
// ---------------------------------------------------------------------------
__global__ __launch_bounds__(1024)
void apply_soft(const float* __restrict__ attn, const float* __restrict__ vthr_g,
                float* __restrict__ spar,
                const float* __restrict__ a1, const float* __restrict__ a2,
                const float* __restrict__ a3, const float* __restrict__ a4)
{
    __shared__ float red[16 * 4];
    __shared__ float ssh[4];
    const int bh = blockIdx.x, t = threadIdx.x;
    const float x = attn[bh * 1024 + t];
    float vthr[4];
    #pragma unroll
    for (int kk = 0; kk < 4; ++kk) vthr[kk] = vthr_g[bh * 8 + kk];
    const float m = vthr_g[bh * 8 + 4];

    float ex = expf(x - m);
    float v4[4];
    #pragma unroll
    for (int kk = 0; kk < 4; ++kk) v4[kk] = (x >= vthr[kk]) ? ex : 0.f;
    #pragma unroll
    for (int off = 32; off; off >>= 1)
        #pragma unroll
        for (int kk = 0; kk < 4; ++kk) v4[kk] += __shfl_down(v4[kk], off);
    const int lane = t & 63, wid = t >> 6;
    if (lane == 0) {
        #pragma unroll
        for (int kk = 0; kk < 4; ++kk) red[wid * 4 + kk] = v4[kk];
    }
    __syncthreads();
    if (t == 0) {
        float s0 = 0, s1 = 0, s2 = 0, s3 = 0;
        for (int ww = 0; ww < 16; ++ww) {
            s0 += red[ww * 4 + 0]; s1 += red[ww * 4 + 1];
            s2 += red[ww * 4 + 2]; s3 += red[ww * 4 + 3];
        }
        ssh[0] = s0; ssh[1] = s1; ssh[2] = s2; ssh[3] = s3;
    }
    __syncthreads();

    float av[4] = {*a1, *a2, *a3, *a4};
    float coef = 0.f;
    #pragma unroll
    for (int kk = 0; kk < 4; ++kk)
        if (x >= vthr[kk]) coef += av[kk] / ssh[kk];
    spar[bh * 1024 + t] = ex * coef;
}

// ---------------------------------------------------------------------------
// K6: M2 fold of Wproj & spar; emit split bf16 in quad-swizzled MFMA A-layout:
// row = b*2048 + s*256 + o (s=hd>>5), slot qt^((o>>1)&3).
// ---------------------------------------------------------------------------
__global__ __launch_bounds__(256)
void build_m2_split(const float* __restrict__ wproj, const float* __restrict__ spar,
                    u16* __restrict__ m2h, u16* __restrict__ m2l)
{
    const int idx = blockIdx.x * 256 + threadIdx.x;  // 0..131071
    const int b = idx >> 16, o = (idx >> 8) & 255, hd = idx & 255;
    const int h = hd >> 5, d = hd & 31;
    const float* wrow = wproj + o * 256 + h * CPH;
    const float* sp = spar + (size_t)(b * 8 + h) * 1024 + d;
    float acc = 0.f;
    #pragma unroll 8
    for (int cc = 0; cc < 32; ++cc)
        acc = fmaf(wrow[cc], sp[cc * 32], acc);
    u16 hi = f2bf(acc);
    u16 lo = f2bf(acc - bf2f(hi));
    const int s = hd >> 5, cslot = hd & 31;
    const int qt = cslot >> 3, e = cslot & 7;
    const int p = (o >> 1) & 3;
    size_t pos = ((size_t)(b * 2048 + s * 256 + o) << 5) + ((qt ^ p) << 3) + e;
    m2h[pos] = hi;
    m2l[pos] = lo;
}

// ---------------------------------------------------------------------------
// launch
// ---------------------------------------------------------------------------
extern "C" void kernel_launch(void* const* d_in, const int* in_sizes, int n_in,
                              void* d_out, int out_size, void* d_ws, size_t ws_size,
                              hipStream_t stream)
{
    const float* x      = (const float*)d_in[0];
    const float* w_qkv  = (const float*)d_in[1];
    const float* w_dw   = (const float*)d_in[2];
    const float* w_proj = (const float*)d_in[3];
    const float* temp   = (const float*)d_in[4];
    const float* a1     = (const float*)d_in[5];
    const float* a2     = (const float*)d_in[6];
    const float* a3     = (const float*)d_in[7];
    const float* a4     = (const float*)d_in[8];

    float* ws = (float*)d_ws;
    u16* qkvb = (u16*)ws;
    u16* vth  = (u16*)(ws + 12582912);
    float* sumsqp = ws;                      // 32*16*64 = 32768 floats
    float* part   = ws + 32768;              // 32*16*1024 = 524288 floats
    float* attn   = ws + 557056;             // 16384 floats
    float* spar   = ws + 573440;             // 16384 floats
    float* vthr_g = ws + 589824;             // 16*8 = 128 floats
    u16* m2h = (u16*)(ws + 589952);          // 131072 u16
    u16* m2l = m2h + 131072;                 // 131072 u16
    float* r1 = ws + (size_t)25165824;
    u16* xth = (u16*)r1;                     // 8388608 u16
    u16* xtl = xth + (size_t)8388608;
    u16* whp = xtl + (size_t)8388608;        // 196608 u16
    u16* wlp = whp + (size_t)196608;
    u16* dwb = (u16*)r1;                     // [2][768][HW] bf16 (after K1')

    // T1+T2 merged: split W + transpose/split x (quad-swizzled)
    prep_inputs<<<2072, 256, 0, stream>>>(x, w_qkv, xth, xtl, whp, wlp);
    // K1': qkv = W_qkv @ x (LDS 2-phase split MFMA, XCD swizzle, bf16 out)
    gemm_mfma_split<true, true, 6><<<1536, 256, 0, stream>>>(
        whp, wlp, xth, xtl, qkvb, 0, 768, (long)NCH * HW);
    // K2: depthwise 3x3, merged: v -> vth (fused transpose) + q,k -> dwb
    dwconv_all<<<5120, 256, 0, stream>>>(qkvb, w_dw, dwb, vth);
    // K4: Gram via direct MFMA + fused sumsq
    gram_mfma<<<dim3(32, 16), 256, 0, stream>>>(dwb, part, sumsqp);
    // K5: finish -> rank (parallel) -> apply
    gram_finish<<<64, 256, 0, stream>>>(part, sumsqp, temp, attn);
    rank4<<<dim3(8, 16), 128, 0, stream>>>(attn, vthr_g);
    apply_soft<<<16, 1024, 0, stream>>>(attn, vthr_g, spar, a1, a2, a3, a4);
    // K6: fold proj @ spar into split-bf16 M2 (swizzled A-layout)
    build_m2_split<<<512, 256, 0, stream>>>(w_proj, spar, m2h, m2l);
    // K7': out = M2 @ v (LDS 2-phase 2-product MFMA, fp32 out)
    gemm_mfma_split<false, false, 2><<<512, 256, 0, stream>>>(
        m2h, m2l, vth, nullptr, d_out, 2048, 256, (long)DIMC * HW);
}